// Round 1
// baseline (4874.103 us; speedup 1.0000x reference)
//
#include <hip/hip_runtime.h>
#include <hip/hip_bf16.h>
#include <math.h>

#define S_LEN 2048
#define HID 3072
#define NHEAD 32
#define NKV 8
#define HDIM 96
#define QKV_N 4608   // 32*96 + 2*8*96
#define NB 32        // S/64 blocks
#define GHDIM 128

// ---------------- fp32 tiled GEMM: C[M,N] = A[M,K] @ B[K,N], all row-major ----
// BM=BN=64, BK=16, 16x16 threads, 4x4 per thread. M,N,K multiples of 64/16.
__global__ __launch_bounds__(256) void sgemm64(const float* __restrict__ A,
                                               const float* __restrict__ B,
                                               float* __restrict__ C,
                                               int M, int N, int K) {
    __shared__ float As[16][65];
    __shared__ float Bs[16][65];
    int tx = threadIdx.x, ty = threadIdx.y;
    int tid = ty * 16 + tx;
    int row0 = blockIdx.y * 64, col0 = blockIdx.x * 64;
    float acc[4][4] = {};
    for (int k0 = 0; k0 < K; k0 += 16) {
        for (int i = tid; i < 64 * 16; i += 256) {
            int m = i >> 4, k = i & 15;
            As[k][m] = A[(size_t)(row0 + m) * K + k0 + k];
        }
        for (int i = tid; i < 16 * 64; i += 256) {
            int k = i >> 6, n = i & 63;
            Bs[k][n] = B[(size_t)(k0 + k) * N + col0 + n];
        }
        __syncthreads();
#pragma unroll
        for (int k = 0; k < 16; ++k) {
            float a[4], b[4];
#pragma unroll
            for (int i = 0; i < 4; i++) a[i] = As[k][ty * 4 + i];
#pragma unroll
            for (int j = 0; j < 4; j++) b[j] = Bs[k][tx * 4 + j];
#pragma unroll
            for (int i = 0; i < 4; i++)
#pragma unroll
                for (int j = 0; j < 4; j++) acc[i][j] += a[i] * b[j];
        }
        __syncthreads();
    }
    for (int i = 0; i < 4; i++)
        for (int j = 0; j < 4; j++)
            C[(size_t)(row0 + ty * 4 + i) * N + col0 + tx * 4 + j] = acc[i][j];
}

// ---------------- k pooling (mean+max over 64 tokens, pre-RoPE) + gate GEMV ---
__global__ __launch_bounds__(128) void pool_gate_k_kernel(const float* __restrict__ qkv,
                                                          const float* __restrict__ gate_wk,
                                                          float* __restrict__ k_gate) {
    int nb = blockIdx.x, h = blockIdx.y;
    int tid = threadIdx.x;
    __shared__ float pool[192];
    if (tid < 96) {
        float s = 0.f, mx = -1e30f;
        for (int i = 0; i < 64; i++) {
            float v = qkv[(size_t)(nb * 64 + i) * QKV_N + HID + h * 96 + tid];
            s += v;
            mx = fmaxf(mx, v);
        }
        pool[tid] = s * (1.f / 64.f);
        pool[96 + tid] = mx;
    }
    __syncthreads();
    float acc = 0.f;
    for (int e = 0; e < 192; e++) acc += pool[e] * gate_wk[e * GHDIM + tid];
    k_gate[(size_t)(nb * NKV + h) * GHDIM + tid] = acc;
}

// ---------------- q pooling (mean over 4 heads x 64 tokens, pre-RoPE) + gate --
__global__ __launch_bounds__(128) void pool_gate_q_kernel(const float* __restrict__ qkv,
                                                          const float* __restrict__ gate_wq,
                                                          float* __restrict__ q_gate) {
    int nb = blockIdx.x, h = blockIdx.y;
    int tid = threadIdx.x;
    __shared__ float pool[96];
    if (tid < 96) {
        float s = 0.f;
        for (int i = 0; i < 64; i++)
            for (int g = 0; g < 4; g++)
                s += qkv[(size_t)(nb * 64 + i) * QKV_N + (h * 4 + g) * 96 + tid];
        pool[tid] = s * (1.f / 256.f);
    }
    __syncthreads();
    float acc = 0.f;
    for (int e = 0; e < 96; e++) acc += pool[e] * gate_wq[e * GHDIM + tid];
    q_gate[(size_t)(nb * NKV + h) * GHDIM + tid] = acc;
}

// ---------------- block gate logits -> softmax -> threshold mask --------------
__global__ __launch_bounds__(64) void blockmask_kernel(const float* __restrict__ q_gate,
                                                       const float* __restrict__ k_gate,
                                                       int* __restrict__ mask) {
    int h = blockIdx.x, qb = blockIdx.y;
    int tid = threadIdx.x;  // kb index, valid < 32
    __shared__ float logits[32];
    if (tid < 32) {
        if (tid <= qb) {
            float acc = 0.f;
            const float* qg = &q_gate[(size_t)(qb * NKV + h) * GHDIM];
            const float* kg = &k_gate[(size_t)(tid * NKV + h) * GHDIM];
            for (int e = 0; e < GHDIM; e++) acc += qg[e] * kg[e];
            logits[tid] = acc * 0.08838834764831845f;  // 128^-0.5
        } else {
            logits[tid] = -1e30f;
        }
    }
    __syncthreads();
    if (tid < 32) {
        float mx = -1e30f;
        for (int j = 0; j <= qb; j++) mx = fmaxf(mx, logits[j]);
        float sum = 0.f;
        for (int j = 0; j <= qb; j++) sum += __expf(logits[j] - mx);
        float p = (tid <= qb) ? __expf(logits[tid] - mx) / sum : 0.f;
        int m = ((p >= 0.03f) && (tid <= qb)) || (tid == qb);
        mask[(h * NB + qb) * NB + tid] = m;
    }
}

// ---------------- RoPE in place on q,k sections of qkv ------------------------
__global__ __launch_bounds__(256) void rope_kernel(float* __restrict__ qkv,
                                                   const float* __restrict__ cosb,
                                                   const float* __restrict__ sinb) {
    int idx = blockIdx.x * blockDim.x + threadIdx.x;
    const int total = S_LEN * 40 * 48;  // 40 heads (32 q + 8 k), 48 rot pairs
    if (idx >= total) return;
    int d = idx % 48;
    int tmp = idx / 48;
    int head = tmp % 40;
    int s = tmp / 40;
    size_t base = (size_t)s * QKV_N + (head < 32 ? head * 96 : HID + (head - 32) * 96);
    float x0 = qkv[base + d];
    float x1 = qkv[base + d + 48];
    float c0 = cosb[s * 96 + d], c1 = cosb[s * 96 + d + 48];
    float s0 = sinb[s * 96 + d], s1 = sinb[s * 96 + d + 48];
    qkv[base + d] = x0 * c0 - x1 * s0;
    qkv[base + d + 48] = x1 * c1 + x0 * s1;
}

// ---------------- block-sparse flash attention --------------------------------
// grid (NB, NHEAD), block 256. Thread: row r = tid/4, col-chunk c = tid&3.
__global__ __launch_bounds__(256) void attn_kernel(const float* __restrict__ qkv,
                                                   const int* __restrict__ mask,
                                                   float* __restrict__ out) {
    int ib = blockIdx.x;
    int hq = blockIdx.y;
    int h = hq >> 2;
    int tid = threadIdx.x;
    int r = tid >> 2;
    int c = tid & 3;
    __shared__ float Qs[64][97];
    __shared__ float Ks[64][97];
    __shared__ float Vs[64][97];
    __shared__ float Ps[64][65];
    for (int i = tid; i < 64 * 96; i += 256) {
        int rr = i / 96, dd = i % 96;
        Qs[rr][dd] = qkv[(size_t)(ib * 64 + rr) * QKV_N + hq * 96 + dd];
    }
    float m_i = -1e30f;
    float l_i = 0.f;
    float acc[24];
#pragma unroll
    for (int j = 0; j < 24; j++) acc[j] = 0.f;
    const float scale = 0.10206207261596575f;  // 96^-0.5

    for (int jb = 0; jb <= ib; ++jb) {
        if (!mask[(h * NB + ib) * NB + jb]) continue;  // block-uniform
        __syncthreads();  // previous PV reads done before overwrite
        for (int i = tid; i < 64 * 96; i += 256) {
            int tt = i / 96, dd = i % 96;
            size_t rowb = (size_t)(jb * 64 + tt) * QKV_N;
            Ks[tt][dd] = qkv[rowb + HID + h * 96 + dd];
            Vs[tt][dd] = qkv[rowb + HID + 768 + h * 96 + dd];
        }
        __syncthreads();
        float sc[16];
#pragma unroll
        for (int t = 0; t < 16; t++) sc[t] = 0.f;
        for (int dd = 0; dd < 96; ++dd) {
            float qd = Qs[r][dd];
#pragma unroll
            for (int t = 0; t < 16; t++) sc[t] += qd * Ks[c * 16 + t][dd];
        }
        float mloc = -1e30f;
#pragma unroll
        for (int t = 0; t < 16; t++) {
            int tcol = c * 16 + t;
            sc[t] *= scale;
            if (jb == ib && tcol > r) sc[t] = -1e30f;
            mloc = fmaxf(mloc, sc[t]);
        }
        mloc = fmaxf(mloc, __shfl_xor(mloc, 1));
        mloc = fmaxf(mloc, __shfl_xor(mloc, 2));
        float m_new = fmaxf(m_i, mloc);
        float alpha = __expf(m_i - m_new);
        float psum = 0.f;
#pragma unroll
        for (int t = 0; t < 16; t++) {
            float p = __expf(sc[t] - m_new);
            Ps[r][c * 16 + t] = p;
            psum += p;
        }
        psum += __shfl_xor(psum, 1);
        psum += __shfl_xor(psum, 2);
        l_i = l_i * alpha + psum;
        m_i = m_new;
#pragma unroll
        for (int j = 0; j < 24; j++) acc[j] *= alpha;
        __syncthreads();
        for (int t = 0; t < 64; t++) {
            float p = Ps[r][t];
#pragma unroll
            for (int j = 0; j < 24; j++) acc[j] += p * Vs[t][c * 24 + j];
        }
    }
    float inv_l = 1.f / l_i;
#pragma unroll
    for (int j = 0; j < 24; j++)
        out[(size_t)(ib * 64 + r) * HID + hq * 96 + c * 24 + j] = acc[j] * inv_l;
}

extern "C" void kernel_launch(void* const* d_in, const int* in_sizes, int n_in,
                              void* d_out, int out_size, void* d_ws, size_t ws_size,
                              hipStream_t stream) {
    const float* hidden  = (const float*)d_in[0];
    const float* cosb    = (const float*)d_in[1];
    const float* sinb    = (const float*)d_in[2];
    const float* qkv_w   = (const float*)d_in[3];
    const float* o_w     = (const float*)d_in[4];
    const float* gate_wq = (const float*)d_in[5];
    const float* gate_wk = (const float*)d_in[6];
    float* out = (float*)d_out;

    float* qkv      = (float*)d_ws;                       // 2048*4608
    float* attn_out = qkv + (size_t)S_LEN * QKV_N;        // 2048*3072
    float* k_gate   = attn_out + (size_t)S_LEN * HID;     // 32*8*128
    float* q_gate   = k_gate + NB * NKV * GHDIM;          // 32*8*128
    int*   mask     = (int*)(q_gate + NB * NKV * GHDIM);  // 8*32*32

    dim3 blk16(16, 16);
    // 1. QKV projection
    sgemm64<<<dim3(QKV_N / 64, S_LEN / 64), blk16, 0, stream>>>(
        hidden, qkv_w, qkv, S_LEN, QKV_N, HID);
    // 2-3. pooled gates (pre-RoPE)
    pool_gate_k_kernel<<<dim3(NB, NKV), 128, 0, stream>>>(qkv, gate_wk, k_gate);
    pool_gate_q_kernel<<<dim3(NB, NKV), 128, 0, stream>>>(qkv, gate_wq, q_gate);
    // 4. block mask
    blockmask_kernel<<<dim3(NKV, NB), 64, 0, stream>>>(q_gate, k_gate, mask);
    // 5. RoPE in place
    const int rope_total = S_LEN * 40 * 48;
    rope_kernel<<<(rope_total + 255) / 256, 256, 0, stream>>>(qkv, cosb, sinb);
    // 6. block-sparse flash attention
    attn_kernel<<<dim3(NB, NHEAD), 256, 0, stream>>>(qkv, mask, attn_out);
    // 7. output projection
    sgemm64<<<dim3(HID / 64, S_LEN / 64), blk16, 0, stream>>>(
        attn_out, o_w, out, S_LEN, HID, HID);
}

// Round 2
// 860.600 us; speedup vs baseline: 5.6636x; 5.6636x over previous
//
#include <hip/hip_runtime.h>
#include <hip/hip_bf16.h>
#include <math.h>

#define S_LEN 2048
#define HID 3072
#define NHEAD 32
#define NKV 8
#define HDIM 96
#define QKV_N 4608   // 32*96 + 2*8*96
#define NB 32        // S/64 blocks
#define GHDIM 128

typedef __attribute__((ext_vector_type(8))) short bf16x8;
typedef __attribute__((ext_vector_type(4))) float f32x4;

__device__ __forceinline__ unsigned short f2bf(float x) {
    unsigned u = __float_as_uint(x);
    u += 0x7fffu + ((u >> 16) & 1u);
    return (unsigned short)(u >> 16);
}
__device__ __forceinline__ unsigned packbf2(float a, float b) {
    return (unsigned)f2bf(a) | ((unsigned)f2bf(b) << 16);
}

// ============ bf16 MFMA GEMM: C_f32[M,N] = A[M,K] @ B_f32[K,N] ==============
// A is fp32 (a_bf16=0, converted while staging) or bf16 row-major (a_bf16=1).
// B is fp32 row-major, transposed+converted during LDS staging.
// Tile 128x128x32, 4 waves in 2x2, each wave 64x64 via 4x4 16x16x32 MFMAs.
__global__ __launch_bounds__(256) void gemm_mfma(const void* __restrict__ Aptr,
                                                 const float* __restrict__ B,
                                                 float* __restrict__ C,
                                                 int M, int N, int K, int a_bf16) {
    __shared__ short As[128][48];  // [m][k], 96B row stride (16B-aligned, 24-bank)
    __shared__ short Bs[128][48];  // [n][k]
    const int tid = threadIdx.x;
    const int lane = tid & 63;
    const int w = tid >> 6;
    const int wm = (w >> 1) * 64;
    const int wn = (w & 1) * 64;
    const int l15 = lane & 15;
    const int quad = lane >> 4;
    const int m0 = blockIdx.y * 128;
    const int n0 = blockIdx.x * 128;
    const float* Af = (const float*)Aptr;
    const unsigned short* Ah = (const unsigned short*)Aptr;

    f32x4 acc[4][4] = {};

    for (int k0 = 0; k0 < K; k0 += 32) {
        __syncthreads();
        if (a_bf16) {
            // 128x32 bf16 = 512 16B-chunks, 2 per thread
#pragma unroll
            for (int j = 0; j < 2; ++j) {
                int idx = tid + j * 256;
                int row = idx >> 2;
                int ch = idx & 3;
                const int4 v = *(const int4*)(Ah + (size_t)(m0 + row) * K + k0 + ch * 8);
                *(int4*)&As[row][ch * 8] = v;
            }
        } else {
            // 128x32 fp32, convert to bf16
#pragma unroll
            for (int j = 0; j < 4; ++j) {
                int idx = tid + j * 256;
                int row = idx >> 3;
                int ch = idx & 7;
                const float4 v = *(const float4*)(Af + (size_t)(m0 + row) * K + k0 + ch * 4);
                int2 p;
                p.x = packbf2(v.x, v.y);
                p.y = packbf2(v.z, v.w);
                *(int2*)&As[row][ch * 4] = p;
            }
        }
        // B: read rows (coalesced along n), write transposed Bs[n][k]
#pragma unroll
        for (int j = 0; j < 4; ++j) {
            int idx = tid + j * 256;
            int n = idx & 127;
            int kq = idx >> 7;  // 0..7, covers k = kq*4 .. +3
            const float* bp = B + (size_t)(k0 + kq * 4) * N + n0 + n;
            float b0 = bp[0];
            float b1 = bp[N];
            float b2 = bp[2 * (size_t)N];
            float b3 = bp[3 * (size_t)N];
            int2 p;
            p.x = packbf2(b0, b1);
            p.y = packbf2(b2, b3);
            *(int2*)&Bs[n][kq * 4] = p;
        }
        __syncthreads();
        bf16x8 afr[4], bfr[4];
#pragma unroll
        for (int mt = 0; mt < 4; ++mt)
            afr[mt] = *(const bf16x8*)&As[wm + mt * 16 + l15][quad * 8];
#pragma unroll
        for (int nt = 0; nt < 4; ++nt)
            bfr[nt] = *(const bf16x8*)&Bs[wn + nt * 16 + l15][quad * 8];
#pragma unroll
        for (int mt = 0; mt < 4; ++mt)
#pragma unroll
            for (int nt = 0; nt < 4; ++nt)
                acc[mt][nt] = __builtin_amdgcn_mfma_f32_16x16x32_bf16(
                    afr[mt], bfr[nt], acc[mt][nt], 0, 0, 0);
    }
    // C/D layout: col = lane&15, row = quad*4 + reg
#pragma unroll
    for (int mt = 0; mt < 4; ++mt)
#pragma unroll
        for (int nt = 0; nt < 4; ++nt)
#pragma unroll
            for (int r = 0; r < 4; ++r) {
                int row = m0 + wm + mt * 16 + quad * 4 + r;
                int col = n0 + wn + nt * 16 + l15;
                C[(size_t)row * N + col] = acc[mt][nt][r];
            }
}

// ---------------- k pooling (mean+max over 64 tokens, pre-RoPE) + gate GEMV ---
__global__ __launch_bounds__(128) void pool_gate_k_kernel(const float* __restrict__ qkv,
                                                          const float* __restrict__ gate_wk,
                                                          float* __restrict__ k_gate) {
    int nb = blockIdx.x, h = blockIdx.y;
    int tid = threadIdx.x;
    __shared__ float pool[192];
    if (tid < 96) {
        float s = 0.f, mx = -1e30f;
        for (int i = 0; i < 64; i++) {
            float v = qkv[(size_t)(nb * 64 + i) * QKV_N + HID + h * 96 + tid];
            s += v;
            mx = fmaxf(mx, v);
        }
        pool[tid] = s * (1.f / 64.f);
        pool[96 + tid] = mx;
    }
    __syncthreads();
    float acc = 0.f;
    for (int e = 0; e < 192; e++) acc += pool[e] * gate_wk[e * GHDIM + tid];
    k_gate[(size_t)(nb * NKV + h) * GHDIM + tid] = acc;
}

// ---------------- q pooling (mean over 4 heads x 64 tokens, pre-RoPE) + gate --
__global__ __launch_bounds__(128) void pool_gate_q_kernel(const float* __restrict__ qkv,
                                                          const float* __restrict__ gate_wq,
                                                          float* __restrict__ q_gate) {
    int nb = blockIdx.x, h = blockIdx.y;
    int tid = threadIdx.x;
    __shared__ float pool[96];
    if (tid < 96) {
        float s = 0.f;
        for (int i = 0; i < 64; i++)
            for (int g = 0; g < 4; g++)
                s += qkv[(size_t)(nb * 64 + i) * QKV_N + (h * 4 + g) * 96 + tid];
        pool[tid] = s * (1.f / 256.f);
    }
    __syncthreads();
    float acc = 0.f;
    for (int e = 0; e < 96; e++) acc += pool[e] * gate_wq[e * GHDIM + tid];
    q_gate[(size_t)(nb * NKV + h) * GHDIM + tid] = acc;
}

// ---------------- block gate logits -> softmax -> threshold mask --------------
__global__ __launch_bounds__(64) void blockmask_kernel(const float* __restrict__ q_gate,
                                                       const float* __restrict__ k_gate,
                                                       int* __restrict__ mask) {
    int h = blockIdx.x, qb = blockIdx.y;
    int tid = threadIdx.x;  // kb index, valid < 32
    __shared__ float logits[32];
    if (tid < 32) {
        if (tid <= qb) {
            float acc = 0.f;
            const float* qg = &q_gate[(size_t)(qb * NKV + h) * GHDIM];
            const float* kg = &k_gate[(size_t)(tid * NKV + h) * GHDIM];
            for (int e = 0; e < GHDIM; e++) acc += qg[e] * kg[e];
            logits[tid] = acc * 0.08838834764831845f;  // 128^-0.5
        } else {
            logits[tid] = -1e30f;
        }
    }
    __syncthreads();
    if (tid < 32) {
        float mx = -1e30f;
        for (int j = 0; j <= qb; j++) mx = fmaxf(mx, logits[j]);
        float sum = 0.f;
        for (int j = 0; j <= qb; j++) sum += __expf(logits[j] - mx);
        float p = (tid <= qb) ? __expf(logits[tid] - mx) / sum : 0.f;
        int m = ((p >= 0.03f) && (tid <= qb)) || (tid == qb);
        mask[(h * NB + qb) * NB + tid] = m;
    }
}

// ---------------- RoPE in place on q,k sections of qkv (fp32) -----------------
__global__ __launch_bounds__(256) void rope_kernel(float* __restrict__ qkv,
                                                   const float* __restrict__ cosb,
                                                   const float* __restrict__ sinb) {
    int idx = blockIdx.x * blockDim.x + threadIdx.x;
    const int total = S_LEN * 40 * 48;  // 40 heads (32 q + 8 k), 48 rot pairs
    if (idx >= total) return;
    int d = idx % 48;
    int tmp = idx / 48;
    int head = tmp % 40;
    int s = tmp / 40;
    size_t base = (size_t)s * QKV_N + (head < 32 ? head * 96 : HID + (head - 32) * 96);
    float x0 = qkv[base + d];
    float x1 = qkv[base + d + 48];
    float c0 = cosb[s * 96 + d], c1 = cosb[s * 96 + d + 48];
    float s0 = sinb[s * 96 + d], s1 = sinb[s * 96 + d + 48];
    qkv[base + d] = x0 * c0 - x1 * s0;
    qkv[base + d + 48] = x1 * c1 + x0 * s1;
}

// ============ MFMA block-sparse flash attention ===============================
// grid (NB, NHEAD), 256 threads = 4 waves; wave w handles Q rows w*16..w*16+15.
// Q frags in registers; K row-major LDS (B-op of QK^T); V transposed LDS
// (B-op of PV); P via LDS round-trip (C-layout -> A-layout).
__global__ __launch_bounds__(256) void attn_mfma(const float* __restrict__ qkv,
                                                 const int* __restrict__ mask,
                                                 unsigned short* __restrict__ out) {
    const int ib = blockIdx.x;
    const int hq = blockIdx.y;
    const int h = hq >> 2;
    const int tid = threadIdx.x;
    const int lane = tid & 63;
    const int w = tid >> 6;
    const int l15 = lane & 15;
    const int quad = lane >> 4;

    __shared__ short Ks[64][104];  // [token][dim], 208B rows (16B-aligned)
    __shared__ short Vt[96][72];   // [dim][token], 144B rows
    __shared__ short Ps[64][72];   // [row][col] P round-trip, per-wave strips

    // Q fragments (post-RoPE): rows ib*64 + w*16 + l15, k = ks*32 + quad*8 .. +7
    bf16x8 qf[3];
    {
        const float* qp = qkv + (size_t)(ib * 64 + w * 16 + l15) * QKV_N + hq * 96;
#pragma unroll
        for (int ks = 0; ks < 3; ++ks) {
            const float4 f0 = *(const float4*)(qp + ks * 32 + quad * 8);
            const float4 f1 = *(const float4*)(qp + ks * 32 + quad * 8 + 4);
            union { bf16x8 v; unsigned u[4]; } tmp;
            tmp.u[0] = packbf2(f0.x, f0.y);
            tmp.u[1] = packbf2(f0.z, f0.w);
            tmp.u[2] = packbf2(f1.x, f1.y);
            tmp.u[3] = packbf2(f1.z, f1.w);
            qf[ks] = tmp.v;
        }
    }

    float m_i[4], l_i[4];
#pragma unroll
    for (int r = 0; r < 4; ++r) { m_i[r] = -1e30f; l_i[r] = 0.f; }
    f32x4 acc_o[6] = {};
    const float scale = 0.10206207261596575f;  // 96^-0.5

    for (int jb = 0; jb <= ib; ++jb) {
        if (!mask[(h * NB + ib) * NB + jb]) continue;  // block-uniform
        __syncthreads();  // previous iteration's LDS reads done
        // stage K tile (64x96 fp32 -> bf16), coalesced
#pragma unroll
        for (int j = 0; j < 6; ++j) {
            int idx = tid + j * 256;
            int tt = idx / 24;
            int c = idx - tt * 24;
            const float4 v = *(const float4*)(qkv + (size_t)(jb * 64 + tt) * QKV_N +
                                              HID + h * 96 + c * 4);
            int2 p;
            p.x = packbf2(v.x, v.y);
            p.y = packbf2(v.z, v.w);
            *(int2*)&Ks[tt][c * 4] = p;
        }
        // stage V transposed: Vt[d][t]; 4 coalesced dword reads per b64 write
#pragma unroll
        for (int j = 0; j < 6; ++j) {
            int idx = tid + j * 256;
            int ttq = idx / 96;
            int d = idx - ttq * 96;
            const float* vp = qkv + (size_t)(jb * 64 + ttq * 4) * QKV_N +
                              HID + 768 + h * 96 + d;
            float v0 = vp[0];
            float v1 = vp[QKV_N];
            float v2 = vp[2 * QKV_N];
            float v3 = vp[3 * QKV_N];
            int2 p;
            p.x = packbf2(v0, v1);
            p.y = packbf2(v2, v3);
            *(int2*)&Vt[d][ttq * 4] = p;
        }
        __syncthreads();

        // QK^T: s[nt] = 16x16 tile, cols nt*16..+15 of this k-block
        f32x4 s[4] = {};
#pragma unroll
        for (int ks = 0; ks < 3; ++ks) {
#pragma unroll
            for (int nt = 0; nt < 4; ++nt) {
                bf16x8 kb = *(const bf16x8*)&Ks[nt * 16 + l15][ks * 32 + quad * 8];
                s[nt] = __builtin_amdgcn_mfma_f32_16x16x32_bf16(qf[ks], kb, s[nt], 0, 0, 0);
            }
        }
        // scale + causal mask (C-layout: col = l15, row = quad*4+r)
#pragma unroll
        for (int nt = 0; nt < 4; ++nt)
#pragma unroll
            for (int r = 0; r < 4; ++r) {
                float v = s[nt][r] * scale;
                if (jb == ib && (nt * 16 + l15) > (w * 16 + quad * 4 + r)) v = -1e30f;
                s[nt][r] = v;
            }
        // online softmax per row (reduce across the 16 lanes of each quad-row)
        float alpha[4];
#pragma unroll
        for (int r = 0; r < 4; ++r) {
            float mx = fmaxf(fmaxf(s[0][r], s[1][r]), fmaxf(s[2][r], s[3][r]));
            mx = fmaxf(mx, __shfl_xor(mx, 1));
            mx = fmaxf(mx, __shfl_xor(mx, 2));
            mx = fmaxf(mx, __shfl_xor(mx, 4));
            mx = fmaxf(mx, __shfl_xor(mx, 8));
            float mnew = fmaxf(m_i[r], mx);
            alpha[r] = __expf(m_i[r] - mnew);
            float ps = 0.f;
#pragma unroll
            for (int nt = 0; nt < 4; ++nt) {
                float p = __expf(s[nt][r] - mnew);
                s[nt][r] = p;
                ps += p;
            }
            ps += __shfl_xor(ps, 1);
            ps += __shfl_xor(ps, 2);
            ps += __shfl_xor(ps, 4);
            ps += __shfl_xor(ps, 8);
            l_i[r] = l_i[r] * alpha[r] + ps;
            m_i[r] = mnew;
        }
#pragma unroll
        for (int t = 0; t < 6; ++t)
#pragma unroll
            for (int r = 0; r < 4; ++r) acc_o[t][r] *= alpha[r];
        // P: C-layout regs -> LDS (per-wave strip, no cross-wave hazard)
#pragma unroll
        for (int nt = 0; nt < 4; ++nt)
#pragma unroll
            for (int r = 0; r < 4; ++r)
                Ps[w * 16 + quad * 4 + r][nt * 16 + l15] = (short)f2bf(s[nt][r]);
        // PV: A = P (A-layout from LDS), B = Vt
#pragma unroll
        for (int ks = 0; ks < 2; ++ks) {
            bf16x8 pa = *(const bf16x8*)&Ps[w * 16 + l15][ks * 32 + quad * 8];
#pragma unroll
            for (int t = 0; t < 6; ++t) {
                bf16x8 vb = *(const bf16x8*)&Vt[t * 16 + l15][ks * 32 + quad * 8];
                acc_o[t] = __builtin_amdgcn_mfma_f32_16x16x32_bf16(pa, vb, acc_o[t], 0, 0, 0);
            }
        }
    }
    // epilogue: normalize, write bf16 attn_out
#pragma unroll
    for (int r = 0; r < 4; ++r) {
        float inv = 1.f / l_i[r];
        int row = ib * 64 + w * 16 + quad * 4 + r;
#pragma unroll
        for (int t = 0; t < 6; ++t) {
            int col = hq * 96 + t * 16 + l15;
            out[(size_t)row * HID + col] = f2bf(acc_o[t][r] * inv);
        }
    }
}

extern "C" void kernel_launch(void* const* d_in, const int* in_sizes, int n_in,
                              void* d_out, int out_size, void* d_ws, size_t ws_size,
                              hipStream_t stream) {
    const float* hidden  = (const float*)d_in[0];
    const float* cosb    = (const float*)d_in[1];
    const float* sinb    = (const float*)d_in[2];
    const float* qkv_w   = (const float*)d_in[3];
    const float* o_w     = (const float*)d_in[4];
    const float* gate_wq = (const float*)d_in[5];
    const float* gate_wk = (const float*)d_in[6];
    float* out = (float*)d_out;

    char* ws = (char*)d_ws;
    float* qkv = (float*)ws;                                       // 2048*4608 f32
    unsigned short* attn_out = (unsigned short*)(ws + 37748736);   // 2048*3072 bf16
    float* k_gate = (float*)(ws + 50331648);                       // 32*8*128 f32
    float* q_gate = k_gate + NB * NKV * GHDIM;
    int* mask = (int*)(q_gate + NB * NKV * GHDIM);

    // 1. QKV projection (fp32 A/B -> bf16 MFMA, fp32 C)
    gemm_mfma<<<dim3(QKV_N / 128, S_LEN / 128), 256, 0, stream>>>(
        hidden, qkv_w, qkv, S_LEN, QKV_N, HID, 0);
    // 2-3. pooled gates (pre-RoPE, fp32 path)
    pool_gate_k_kernel<<<dim3(NB, NKV), 128, 0, stream>>>(qkv, gate_wk, k_gate);
    pool_gate_q_kernel<<<dim3(NB, NKV), 128, 0, stream>>>(qkv, gate_wq, q_gate);
    // 4. block mask
    blockmask_kernel<<<dim3(NKV, NB), 64, 0, stream>>>(q_gate, k_gate, mask);
    // 5. RoPE in place (fp32)
    const int rope_total = S_LEN * 40 * 48;
    rope_kernel<<<(rope_total + 255) / 256, 256, 0, stream>>>(qkv, cosb, sinb);
    // 6. MFMA block-sparse flash attention -> bf16
    attn_mfma<<<dim3(NB, NHEAD), 256, 0, stream>>>(qkv, mask, attn_out);
    // 7. output projection (bf16 A, fp32 B -> fp32 C)
    gemm_mfma<<<dim3(HID / 128, S_LEN / 128), 256, 0, stream>>>(
        attn_out, o_w, out, S_LEN, HID, HID, 1);
}

// Round 3
// 411.780 us; speedup vs baseline: 11.8367x; 2.0900x over previous
//
#include <hip/hip_runtime.h>
#include <hip/hip_bf16.h>
#include <math.h>

#define S_LEN 2048
#define HID 3072
#define NHEAD 32
#define NKV 8
#define HDIM 96
#define QKV_N 4608   // 32*96 + 2*8*96
#define NB 32        // S/64 blocks
#define GHDIM 128

typedef __attribute__((ext_vector_type(8))) short bf16x8;
typedef __attribute__((ext_vector_type(4))) float f32x4;
typedef unsigned short ushort_t;

__device__ __forceinline__ unsigned short f2bf(float x) {
    unsigned u = __float_as_uint(x);
    u += 0x7fffu + ((u >> 16) & 1u);
    return (unsigned short)(u >> 16);
}
__device__ __forceinline__ unsigned packbf2(float a, float b) {
    return (unsigned)f2bf(a) | ((unsigned)f2bf(b) << 16);
}

#define GLOBAL_AS __attribute__((address_space(1)))
#define LDS_AS __attribute__((address_space(3)))
// async global->LDS, 16B per lane; lds dest = wave-uniform base + lane*16
__device__ __forceinline__ void gl_lds16(const void* g, void* l) {
    __builtin_amdgcn_global_load_lds((const GLOBAL_AS unsigned int*)g,
                                     (LDS_AS unsigned int*)l, 16, 0, 0);
}

// ============ bf16 MFMA GEMM (m97 structure): C_f32[M,N] = A[M,K] @ Bt[N,K]^T
// Tile 128x128, BK=64. global_load_lds width=16 staging, XOR-swizzled chunks.
__global__ __launch_bounds__(256, 2) void gemm_bf16(const ushort_t* __restrict__ A,
                                                    const ushort_t* __restrict__ Bt,
                                                    float* __restrict__ C,
                                                    int M, int N, int K) {
    __shared__ ushort_t As[128 * 64];
    __shared__ ushort_t Bs[128 * 64];
    const int tid = threadIdx.x;
    const int lane = tid & 63;
    const int w = tid >> 6;
    const int wm = (w >> 1) * 64;
    const int wn = (w & 1) * 64;
    const int l15 = lane & 15;
    const int quad = lane >> 4;
    const int m0 = blockIdx.y * 128;
    const int n0 = blockIdx.x * 128;

    f32x4 acc[4][4] = {};

    for (int k0 = 0; k0 < K; k0 += 64) {
        __syncthreads();
        // stage A: 1024 16B-chunks; slot s holds global chunk (row=s>>3, kc=(s&7)^(row&7))
#pragma unroll
        for (int j = 0; j < 4; ++j) {
            int s = j * 256 + w * 64 + lane;
            int row = s >> 3;
            int kc = (s & 7) ^ (row & 7);
            gl_lds16(A + (size_t)(m0 + row) * K + k0 + kc * 8,
                     &As[(j * 256 + w * 64) * 8]);
        }
#pragma unroll
        for (int j = 0; j < 4; ++j) {
            int s = j * 256 + w * 64 + lane;
            int row = s >> 3;
            int kc = (s & 7) ^ (row & 7);
            gl_lds16(Bt + (size_t)(n0 + row) * K + k0 + kc * 8,
                     &Bs[(j * 256 + w * 64) * 8]);
        }
        __syncthreads();
        bf16x8 af[2][4], bf[2][4];
#pragma unroll
        for (int mt = 0; mt < 4; ++mt) {
            int row = wm + mt * 16 + l15;
            int rx = row & 7;
#pragma unroll
            for (int ph = 0; ph < 2; ++ph)
                af[ph][mt] = *(const bf16x8*)&As[(row * 8 + ((ph * 4 + quad) ^ rx)) * 8];
        }
#pragma unroll
        for (int nt = 0; nt < 4; ++nt) {
            int row = wn + nt * 16 + l15;
            int rx = row & 7;
#pragma unroll
            for (int ph = 0; ph < 2; ++ph)
                bf[ph][nt] = *(const bf16x8*)&Bs[(row * 8 + ((ph * 4 + quad) ^ rx)) * 8];
        }
#pragma unroll
        for (int ph = 0; ph < 2; ++ph)
#pragma unroll
            for (int mt = 0; mt < 4; ++mt)
#pragma unroll
                for (int nt = 0; nt < 4; ++nt)
                    acc[mt][nt] = __builtin_amdgcn_mfma_f32_16x16x32_bf16(
                        af[ph][mt], bf[ph][nt], acc[mt][nt], 0, 0, 0);
    }
#pragma unroll
    for (int mt = 0; mt < 4; ++mt)
#pragma unroll
        for (int nt = 0; nt < 4; ++nt)
#pragma unroll
            for (int r = 0; r < 4; ++r) {
                int row = m0 + wm + mt * 16 + quad * 4 + r;
                int col = n0 + wn + nt * 16 + l15;
                C[(size_t)row * N + col] = acc[mt][nt][r];
            }
}

// ---------------- fp32 -> bf16 elementwise convert ----------------------------
__global__ __launch_bounds__(256) void conv_bf16(const float* __restrict__ X,
                                                 ushort_t* __restrict__ Y, int n4) {
    int i = blockIdx.x * 256 + threadIdx.x;
    if (i >= n4) return;
    const float4 v = *(const float4*)(X + (size_t)i * 4);
    int2 p;
    p.x = (int)packbf2(v.x, v.y);
    p.y = (int)packbf2(v.z, v.w);
    *(int2*)(Y + (size_t)i * 4) = p;
}

// ---------------- W f32 [K][N] -> Wt bf16 [N][K] (tiled 64x64) ---------------
__global__ __launch_bounds__(256) void transpose_convert(const float* __restrict__ W,
                                                         ushort_t* __restrict__ Wt,
                                                         int K, int N) {
    __shared__ float Ts[64][65];
    const int k0 = blockIdx.y * 64, n0 = blockIdx.x * 64;
    const int tid = threadIdx.x;
    {
        int r = tid >> 2, cq = tid & 3;
#pragma unroll
        for (int i = 0; i < 4; ++i) {
            int c = cq * 16 + i * 4;
            const float4 v = *(const float4*)(W + (size_t)(k0 + r) * N + n0 + c);
            Ts[r][c] = v.x; Ts[r][c + 1] = v.y; Ts[r][c + 2] = v.z; Ts[r][c + 3] = v.w;
        }
    }
    __syncthreads();
#pragma unroll
    for (int it = 0; it < 2; ++it) {
        int n = (tid >> 3) + it * 32;
        int kc = tid & 7;
        int4 r;
        r.x = (int)(packbf2(Ts[kc * 8 + 0][n], Ts[kc * 8 + 1][n]));
        r.y = (int)(packbf2(Ts[kc * 8 + 2][n], Ts[kc * 8 + 3][n]));
        r.z = (int)(packbf2(Ts[kc * 8 + 4][n], Ts[kc * 8 + 5][n]));
        r.w = (int)(packbf2(Ts[kc * 8 + 6][n], Ts[kc * 8 + 7][n]));
        *(int4*)(Wt + (size_t)(n0 + n) * K + k0 + kc * 8) = r;
    }
}

// ---------------- k pooling (mean+max over 64 tokens, pre-RoPE) + gate GEMV ---
__global__ __launch_bounds__(128) void pool_gate_k_kernel(const float* __restrict__ qkv,
                                                          const float* __restrict__ gate_wk,
                                                          float* __restrict__ k_gate) {
    int nb = blockIdx.x, h = blockIdx.y;
    int tid = threadIdx.x;
    __shared__ float pool[192];
    if (tid < 96) {
        float s = 0.f, mx = -1e30f;
        for (int i = 0; i < 64; i++) {
            float v = qkv[(size_t)(nb * 64 + i) * QKV_N + HID + h * 96 + tid];
            s += v;
            mx = fmaxf(mx, v);
        }
        pool[tid] = s * (1.f / 64.f);
        pool[96 + tid] = mx;
    }
    __syncthreads();
    float acc = 0.f;
    for (int e = 0; e < 192; e++) acc += pool[e] * gate_wk[e * GHDIM + tid];
    k_gate[(size_t)(nb * NKV + h) * GHDIM + tid] = acc;
}

// ---------------- q pooling (mean over 4 heads x 64 tokens, pre-RoPE) + gate --
__global__ __launch_bounds__(128) void pool_gate_q_kernel(const float* __restrict__ qkv,
                                                          const float* __restrict__ gate_wq,
                                                          float* __restrict__ q_gate) {
    int nb = blockIdx.x, h = blockIdx.y;
    int tid = threadIdx.x;
    __shared__ float pool[96];
    if (tid < 96) {
        float s = 0.f;
        for (int i = 0; i < 64; i++)
            for (int g = 0; g < 4; g++)
                s += qkv[(size_t)(nb * 64 + i) * QKV_N + (h * 4 + g) * 96 + tid];
        pool[tid] = s * (1.f / 256.f);
    }
    __syncthreads();
    float acc = 0.f;
    for (int e = 0; e < 96; e++) acc += pool[e] * gate_wq[e * GHDIM + tid];
    q_gate[(size_t)(nb * NKV + h) * GHDIM + tid] = acc;
}

// ---------------- block gate logits -> softmax -> threshold mask --------------
__global__ __launch_bounds__(64) void blockmask_kernel(const float* __restrict__ q_gate,
                                                       const float* __restrict__ k_gate,
                                                       int* __restrict__ mask) {
    int h = blockIdx.x, qb = blockIdx.y;
    int tid = threadIdx.x;
    __shared__ float logits[32];
    if (tid < 32) {
        if (tid <= qb) {
            float acc = 0.f;
            const float* qg = &q_gate[(size_t)(qb * NKV + h) * GHDIM];
            const float* kg = &k_gate[(size_t)(tid * NKV + h) * GHDIM];
            for (int e = 0; e < GHDIM; e++) acc += qg[e] * kg[e];
            logits[tid] = acc * 0.08838834764831845f;
        } else {
            logits[tid] = -1e30f;
        }
    }
    __syncthreads();
    if (tid < 32) {
        float mx = -1e30f;
        for (int j = 0; j <= qb; j++) mx = fmaxf(mx, logits[j]);
        float sum = 0.f;
        for (int j = 0; j <= qb; j++) sum += __expf(logits[j] - mx);
        float p = (tid <= qb) ? __expf(logits[tid] - mx) / sum : 0.f;
        int m = ((p >= 0.03f) && (tid <= qb)) || (tid == qb);
        mask[(h * NB + qb) * NB + tid] = m;
    }
}

// ---------------- RoPE q -> Qb bf16 [S][NHEAD*96] -----------------------------
__global__ __launch_bounds__(256) void rope_q_kernel(const float* __restrict__ qkv,
                                                     const float* __restrict__ cosb,
                                                     const float* __restrict__ sinb,
                                                     ushort_t* __restrict__ Qb) {
    int idx = blockIdx.x * 256 + threadIdx.x;  // total S*32*48
    int d = idx % 48;
    int tmp = idx / 48;
    int head = tmp % 32;
    int s = tmp / 32;
    size_t base = (size_t)s * QKV_N + head * 96;
    float x0 = qkv[base + d];
    float x1 = qkv[base + d + 48];
    float c0 = cosb[s * 96 + d], c1 = cosb[s * 96 + d + 48];
    float s0 = sinb[s * 96 + d], s1 = sinb[s * 96 + d + 48];
    size_t ob = (size_t)s * HID + head * 96;
    Qb[ob + d] = f2bf(x0 * c0 - x1 * s0);
    Qb[ob + d + 48] = f2bf(x1 * c1 + x0 * s1);
}

// ---------------- RoPE k -> Kb bf16 [NKV][S][128] (d-padded) ------------------
__global__ __launch_bounds__(256) void rope_k_kernel(const float* __restrict__ qkv,
                                                     const float* __restrict__ cosb,
                                                     const float* __restrict__ sinb,
                                                     ushort_t* __restrict__ Kb) {
    int idx = blockIdx.x * 256 + threadIdx.x;  // total S*8*48
    int d = idx % 48;
    int tmp = idx / 48;
    int h = tmp % 8;
    int s = tmp / 8;
    size_t base = (size_t)s * QKV_N + HID + h * 96;
    float x0 = qkv[base + d];
    float x1 = qkv[base + d + 48];
    float c0 = cosb[s * 96 + d], c1 = cosb[s * 96 + d + 48];
    float s0 = sinb[s * 96 + d], s1 = sinb[s * 96 + d + 48];
    size_t ob = ((size_t)h * S_LEN + s) * 128;
    Kb[ob + d] = f2bf(x0 * c0 - x1 * s0);
    Kb[ob + d + 48] = f2bf(x1 * c1 + x0 * s1);
}

// ---------------- V transpose -> Vtb bf16 [NKV][96][S] ------------------------
__global__ __launch_bounds__(256) void transpose_v_kernel(const float* __restrict__ qkv,
                                                          ushort_t* __restrict__ Vtb) {
    __shared__ float Vs[64][97];
    const int ibk = blockIdx.x, h = blockIdx.y;
    const int tid = threadIdx.x;
    {
        int t = tid >> 2, cq = tid & 3;
#pragma unroll
        for (int i = 0; i < 6; ++i) {
            int c = cq * 24 + i * 4;
            const float4 v = *(const float4*)(qkv + (size_t)(ibk * 64 + t) * QKV_N +
                                              HID + 768 + h * 96 + c);
            Vs[t][c] = v.x; Vs[t][c + 1] = v.y; Vs[t][c + 2] = v.z; Vs[t][c + 3] = v.w;
        }
    }
    __syncthreads();
#pragma unroll
    for (int it = 0; it < 3; ++it) {
        int s = tid + it * 256;
        int d = s >> 3, tc = s & 7;
        int4 r;
        r.x = (int)(packbf2(Vs[tc * 8 + 0][d], Vs[tc * 8 + 1][d]));
        r.y = (int)(packbf2(Vs[tc * 8 + 2][d], Vs[tc * 8 + 3][d]));
        r.z = (int)(packbf2(Vs[tc * 8 + 4][d], Vs[tc * 8 + 5][d]));
        r.w = (int)(packbf2(Vs[tc * 8 + 6][d], Vs[tc * 8 + 7][d]));
        *(int4*)(Vtb + ((size_t)h * 96 + d) * S_LEN + ibk * 64 + tc * 8) = r;
    }
}

// ============ MFMA block-sparse flash attention (bf16 inputs) =================
// grid (NHEAD, NB) with ib reversed (heavy blocks first). 4 waves/block.
__global__ __launch_bounds__(256) void attn_mfma(const ushort_t* __restrict__ Qb,
                                                 const ushort_t* __restrict__ Kb,
                                                 const ushort_t* __restrict__ Vtb,
                                                 const int* __restrict__ mask,
                                                 ushort_t* __restrict__ out) {
    const int hq = blockIdx.x;
    const int ib = NB - 1 - blockIdx.y;
    const int h = hq >> 2;
    const int tid = threadIdx.x;
    const int lane = tid & 63;
    const int w = tid >> 6;
    const int l15 = lane & 15;
    const int quad = lane >> 4;

    __shared__ ushort_t Ks[64 * 128];  // [t][dc-chunk swizzled]
    __shared__ ushort_t Vt[96 * 64];   // [d][tc-chunk swizzled]
    __shared__ ushort_t Ps[64][72];

    bf16x8 qf[3];
    {
        const ushort_t* qp = Qb + (size_t)(ib * 64 + w * 16 + l15) * HID + hq * 96;
#pragma unroll
        for (int ks = 0; ks < 3; ++ks)
            qf[ks] = *(const bf16x8*)(qp + ks * 32 + quad * 8);
    }

    float m_i[4], l_i[4];
#pragma unroll
    for (int r = 0; r < 4; ++r) { m_i[r] = -1e30f; l_i[r] = 0.f; }
    f32x4 acc_o[6] = {};
    const float scale = 0.10206207261596575f;

    const ushort_t* kbase = Kb + (size_t)h * S_LEN * 128;
    const ushort_t* vbase = Vtb + (size_t)h * 96 * S_LEN;

    for (int jb = 0; jb <= ib; ++jb) {
        if (!mask[(h * NB + ib) * NB + jb]) continue;
        __syncthreads();
        // stage K tile 64x128 bf16 (pad cols never read): 1024 chunks
#pragma unroll
        for (int j = 0; j < 4; ++j) {
            int s = j * 256 + w * 64 + lane;
            int t = s >> 4;
            int dc = (s & 15) ^ (t & 7);
            gl_lds16(kbase + (size_t)(jb * 64 + t) * 128 + dc * 8,
                     &Ks[(j * 256 + w * 64) * 8]);
        }
        // stage V^T tile 96x64 bf16: 768 chunks
#pragma unroll
        for (int j = 0; j < 3; ++j) {
            int s = j * 256 + w * 64 + lane;
            int d = s >> 3;
            int tc = (s & 7) ^ (d & 7);
            gl_lds16(vbase + (size_t)d * S_LEN + jb * 64 + tc * 8,
                     &Vt[(j * 256 + w * 64) * 8]);
        }
        __syncthreads();

        // QK^T
        f32x4 s4[4] = {};
#pragma unroll
        for (int ks = 0; ks < 3; ++ks)
#pragma unroll
            for (int nt = 0; nt < 4; ++nt) {
                int t = nt * 16 + l15;
                int slot = (ks * 4 + quad) ^ (t & 7);
                bf16x8 kb = *(const bf16x8*)&Ks[(t * 16 + slot) * 8];
                s4[nt] = __builtin_amdgcn_mfma_f32_16x16x32_bf16(qf[ks], kb, s4[nt], 0, 0, 0);
            }
#pragma unroll
        for (int nt = 0; nt < 4; ++nt)
#pragma unroll
            for (int r = 0; r < 4; ++r) {
                float v = s4[nt][r] * scale;
                if (jb == ib && (nt * 16 + l15) > (w * 16 + quad * 4 + r)) v = -1e30f;
                s4[nt][r] = v;
            }
        float alpha[4];
#pragma unroll
        for (int r = 0; r < 4; ++r) {
            float mx = fmaxf(fmaxf(s4[0][r], s4[1][r]), fmaxf(s4[2][r], s4[3][r]));
            mx = fmaxf(mx, __shfl_xor(mx, 1));
            mx = fmaxf(mx, __shfl_xor(mx, 2));
            mx = fmaxf(mx, __shfl_xor(mx, 4));
            mx = fmaxf(mx, __shfl_xor(mx, 8));
            float mnew = fmaxf(m_i[r], mx);
            alpha[r] = __expf(m_i[r] - mnew);
            float ps = 0.f;
#pragma unroll
            for (int nt = 0; nt < 4; ++nt) {
                float p = __expf(s4[nt][r] - mnew);
                s4[nt][r] = p;
                ps += p;
            }
            ps += __shfl_xor(ps, 1);
            ps += __shfl_xor(ps, 2);
            ps += __shfl_xor(ps, 4);
            ps += __shfl_xor(ps, 8);
            l_i[r] = l_i[r] * alpha[r] + ps;
            m_i[r] = mnew;
        }
#pragma unroll
        for (int t = 0; t < 6; ++t)
#pragma unroll
            for (int r = 0; r < 4; ++r) acc_o[t][r] *= alpha[r];
#pragma unroll
        for (int nt = 0; nt < 4; ++nt)
#pragma unroll
            for (int r = 0; r < 4; ++r)
                Ps[w * 16 + quad * 4 + r][nt * 16 + l15] = (short)f2bf(s4[nt][r]);
        // PV
#pragma unroll
        for (int ks = 0; ks < 2; ++ks) {
            bf16x8 pa = *(const bf16x8*)&Ps[w * 16 + l15][ks * 32 + quad * 8];
#pragma unroll
            for (int t = 0; t < 6; ++t) {
                int d = t * 16 + l15;
                int slot = (ks * 4 + quad) ^ (d & 7);
                bf16x8 vb = *(const bf16x8*)&Vt[(d * 8 + slot) * 8];
                acc_o[t] = __builtin_amdgcn_mfma_f32_16x16x32_bf16(pa, vb, acc_o[t], 0, 0, 0);
            }
        }
    }
#pragma unroll
    for (int r = 0; r < 4; ++r) {
        float inv = 1.f / l_i[r];
        int row = ib * 64 + w * 16 + quad * 4 + r;
#pragma unroll
        for (int t = 0; t < 6; ++t)
            out[(size_t)row * HID + hq * 96 + t * 16 + l15] = f2bf(acc_o[t][r] * inv);
    }
}

extern "C" void kernel_launch(void* const* d_in, const int* in_sizes, int n_in,
                              void* d_out, int out_size, void* d_ws, size_t ws_size,
                              hipStream_t stream) {
    const float* hidden  = (const float*)d_in[0];
    const float* cosb    = (const float*)d_in[1];
    const float* sinb    = (const float*)d_in[2];
    const float* qkv_w   = (const float*)d_in[3];
    const float* o_w     = (const float*)d_in[4];
    const float* gate_wq = (const float*)d_in[5];
    const float* gate_wk = (const float*)d_in[6];
    float* out = (float*)d_out;

    char* ws = (char*)d_ws;
    float*    qkv   = (float*)ws;                          // 37,748,736 B
    ushort_t* h_bf  = (ushort_t*)(ws + 37748736);          // 12,582,912 B (later reused as Qb)
    ushort_t* w1t   = (ushort_t*)(ws + 50331648);          // 28,311,552 B (later reused as o_wt)
    ushort_t* attn_out = (ushort_t*)(ws + 78643200);       // 12,582,912 B
    ushort_t* Kb    = (ushort_t*)(ws + 91226112);          //  4,194,304 B
    ushort_t* Vtb   = (ushort_t*)(ws + 95420416);          //  3,145,728 B
    float* k_gate   = (float*)(ws + 98566144);             //    131,072 B
    float* q_gate   = (float*)(ws + 98697216);             //    131,072 B
    int*   mask     = (int*)(ws + 98828288);               //     32,768 B
    ushort_t* Qb    = h_bf;       // alias: h_bf dead after gemm1
    ushort_t* o_wt  = w1t;        // alias: w1t dead after gemm1

    // prep for QKV GEMM
    conv_bf16<<<(S_LEN * HID / 4 + 255) / 256, 256, 0, stream>>>(hidden, h_bf, S_LEN * HID / 4);
    transpose_convert<<<dim3(QKV_N / 64, HID / 64), 256, 0, stream>>>(qkv_w, w1t, HID, QKV_N);
    // 1. QKV projection -> f32 qkv
    gemm_bf16<<<dim3(QKV_N / 128, S_LEN / 128), 256, 0, stream>>>(h_bf, w1t, qkv, S_LEN, QKV_N, HID);
    // 2-4. pooled gates + mask (pre-RoPE, fp32)
    pool_gate_k_kernel<<<dim3(NB, NKV), 128, 0, stream>>>(qkv, gate_wk, k_gate);
    pool_gate_q_kernel<<<dim3(NB, NKV), 128, 0, stream>>>(qkv, gate_wq, q_gate);
    blockmask_kernel<<<dim3(NKV, NB), 64, 0, stream>>>(q_gate, k_gate, mask);
    // 5. RoPE + repack to bf16 attention layouts
    rope_q_kernel<<<S_LEN * 32 * 48 / 256, 256, 0, stream>>>(qkv, cosb, sinb, Qb);
    rope_k_kernel<<<S_LEN * 8 * 48 / 256, 256, 0, stream>>>(qkv, cosb, sinb, Kb);
    transpose_v_kernel<<<dim3(NB, NKV), 256, 0, stream>>>(qkv, Vtb);
    // prep O-GEMM weights (after gemm1: reuses w1t space)
    transpose_convert<<<dim3(HID / 64, HID / 64), 256, 0, stream>>>(o_w, o_wt, HID, HID);
    // 6. block-sparse flash attention -> bf16
    attn_mfma<<<dim3(NHEAD, NB), 256, 0, stream>>>(Qb, Kb, Vtb, mask, attn_out);
    // 7. output projection
    gemm_bf16<<<dim3(HID / 128, S_LEN / 128), 256, 0, stream>>>(attn_out, o_wt, out, S_LEN, HID, HID);
}